// Round 8
// baseline (832.610 us; speedup 1.0000x reference)
//
#include <hip/hip_runtime.h>
#include <cstddef>

typedef __bf16 bf16;
typedef __bf16 bf16x8 __attribute__((ext_vector_type(8)));
typedef float  f32x4  __attribute__((ext_vector_type(4)));
typedef unsigned short u16;
typedef unsigned long long u64;

#define MFMA16x16(a, b, c) __builtin_amdgcn_mfma_f32_16x16x32_bf16((a), (b), (c), 0, 0, 0)

namespace {
constexpr int BB   = 4;     // batch
constexpr int CIN  = 128;   // input channels
constexpr int NPT  = 4096;  // points
constexpr int KNBR = 16;    // neighbors
constexpr int HED  = 128;   // hidden (edge mlp out)
constexpr int COUT = 256;   // output channels
}

// ordered-float transform: monotone uint32 over all finite floats
__device__ __forceinline__ unsigned int ord_f32(float f) {
  unsigned int b = __float_as_uint(f);
  return b ^ (0x80000000u | (unsigned int)((int)b >> 31));
}
__device__ __forceinline__ u64 mk_key(float d, int m) {
  return ((u64)ord_f32(d) << 32) | (unsigned int)m;
}

// branch-free bitonic sort of 16 u64 keys, ascending
__device__ __forceinline__ void sort16(u64* k) {
  #pragma unroll
  for (int sz = 2; sz <= 16; sz <<= 1) {
    #pragma unroll
    for (int st = sz >> 1; st > 0; st >>= 1) {
      #pragma unroll
      for (int i = 0; i < 16; ++i) {
        const int j = i ^ st;
        if (j > i) {
          const bool up = ((i & sz) == 0);
          const u64 a = k[i], c = k[j];
          const bool sw = up ? (a > c) : (a < c);
          k[i] = sw ? c : a;
          k[j] = sw ? a : c;
        }
      }
    }
  }
}

// R (sorted asc 16) <- lowest 16 of R ∪ B (B sorted asc), sorted asc
__device__ __forceinline__ void merge16(u64* R, const u64* B) {
  u64 t[16];
  #pragma unroll
  for (int i = 0; i < 16; ++i) {
    const u64 a = R[i], c = B[15 - i];
    t[i] = (a < c) ? a : c;          // half-cleaner: lower half, bitonic
  }
  #pragma unroll
  for (int st = 8; st > 0; st >>= 1) {
    #pragma unroll
    for (int i = 0; i < 16; ++i) {
      const int j = i ^ st;
      if (j > i) {
        const u64 a = t[i], c = t[j];
        const bool sw = a > c;
        t[i] = sw ? c : a;
        t[j] = sw ? a : c;
      }
    }
  }
  #pragma unroll
  for (int i = 0; i < 16; ++i) R[i] = t[i];
}

// ---------------------------------------------------------------------------
// W0: convert the three GEMM weight matrices fp32 -> bf16 (each 32768 elems)
// ---------------------------------------------------------------------------
__global__ __launch_bounds__(256) void k_wconv(const float* __restrict__ We,
                                               const float* __restrict__ Wf,
                                               const float* __restrict__ Wr,
                                               bf16* __restrict__ Web,
                                               bf16* __restrict__ Wfb,
                                               bf16* __restrict__ Wrb) {
  const int i = blockIdx.x * 256 + threadIdx.x;   // [0, 3*32768)
  const int a = i >> 15;
  const int j = i & 32767;
  const float* src = (a == 0) ? We : (a == 1) ? Wf : Wr;
  bf16*        dst = (a == 0) ? Web : (a == 1) ? Wfb : Wrb;
  dst[j] = (bf16)src[j];
}

// ---------------------------------------------------------------------------
// K0: transpose x (B,Cin,N) fp32 -> xt_hi/xt_lo (B,N,Cin) bf16 split, and
//     sq[b][n] = sum_c x^2 in fp32 (matches reference's fp32 sq).
// ---------------------------------------------------------------------------
__global__ __launch_bounds__(256) void k_prep(const float* __restrict__ x,
                                              bf16* __restrict__ xh,
                                              bf16* __restrict__ xl,
                                              float* __restrict__ sq) {
  __shared__ __attribute__((aligned(16))) bf16 th[64][136];
  __shared__ __attribute__((aligned(16))) bf16 tl[64][136];
  __shared__ float sqp[4][64];
  const int tid = threadIdx.x;
  const int b   = blockIdx.x >> 6;
  const int n0  = (blockIdx.x & 63) << 6;
  const int nl  = tid & 63;
  const int cg  = tid >> 6;
  const float* xb = x + (size_t)b * CIN * NPT;
  float acc = 0.f;
  #pragma unroll
  for (int rep = 0; rep < 32; ++rep) {
    const int c = rep * 4 + cg;
    const float v = xb[(size_t)c * NPT + n0 + nl];
    const bf16 h = (bf16)v;
    const bf16 l = (bf16)(v - (float)h);
    acc += v * v;
    th[nl][c] = h;
    tl[nl][c] = l;
  }
  sqp[cg][nl] = acc;
  __syncthreads();
  bf16* xho = xh + ((size_t)b * NPT + n0) * CIN;
  bf16* xlo = xl + ((size_t)b * NPT + n0) * CIN;
  #pragma unroll
  for (int rep = 0; rep < 32; ++rep) {
    const int e = rep * 256 + tid;
    const int r = e >> 7;
    const int c = e & 127;
    xho[(size_t)r * CIN + c] = th[r][c];
    xlo[(size_t)r * CIN + c] = tl[r][c];
  }
  if (tid < 64) {
    sq[b * NPT + n0 + tid] = sqp[0][tid] + sqp[1][tid] + sqp[2][tid] + sqp[3][tid];
  }
}

// ---------------------------------------------------------------------------
// K1: KNN v8. Block = 512 threads (8 waves) over 32 queries; wave w scans
// cands [w*512,(w+1)*512) (8 tiles of 64). Dual 16-query subtiles per wave
// amortize candidate loads 2x (round-4 result: bytes/work beats wave count).
// MFMA A=candidates, B=queries -> Gram in accumulators. Per lane per tile:
// 16 packed u64 keys (ord(d)<<32|idx) bitonic-sorted, merged (lowest-16) into
// running lists. Cross-quad merge via shfl_xor butterfly; cross-wave via
// 33 KB LDS 3-level tree. launch_bounds(512,4) caps VGPR at 128 (round-4-
// proven feasible) -> 2 blocks/CU x 8 waves = 16 waves/CU.
// Key order = lexicographic (d, idx) -> exact lax.top_k tie semantics.
// Split-bf16 (hh+hl+lh) Gram: d2 err ~1e-4 << rank-16/17 gap.
// ---------------------------------------------------------------------------
__global__ __launch_bounds__(512, 4) void k_knn(const bf16* __restrict__ xh,
                                                const bf16* __restrict__ xl,
                                                const float* __restrict__ sq,
                                                int* __restrict__ knn_idx) {
  __shared__ u64 Lk[32][130];   // 32 queries x 8 wave-runs x 16 keys (+pad)
  const int tid  = threadIdx.x;
  const int w    = tid >> 6;                 // 0..7
  const int lane = tid & 63;
  const int col  = lane & 15;
  const int quad = lane >> 4;
  const int b    = blockIdx.x >> 7;          // 128 blocks per batch
  const int q0   = (blockIdx.x & 127) << 5;  // 32 queries per block
  const bf16*  xhb = xh + (size_t)b * NPT * CIN;
  const bf16*  xlb = xl + (size_t)b * NPT * CIN;
  const float* sqb = sq + b * NPT;

  // query fragments (B operand), 2 subtiles of 16 queries
  bf16x8 qh[2][4], ql[2][4];
  float sqn[2];
  #pragma unroll
  for (int t = 0; t < 2; ++t) {
    const bf16* qrh = xhb + (size_t)(q0 + t * 16 + col) * CIN + quad * 8;
    const bf16* qrl = xlb + (size_t)(q0 + t * 16 + col) * CIN + quad * 8;
    #pragma unroll
    for (int ks = 0; ks < 4; ++ks) {
      qh[t][ks] = *(const bf16x8*)(qrh + ks * 32);
      ql[t][ks] = *(const bf16x8*)(qrl + ks * 32);
    }
    sqn[t] = sqb[q0 + t * 16 + col];
  }

  u64 R0[16], R1[16];
  const int cbase = w << 9;                  // 512 cands per wave
  for (int mt = 0; mt < 8; ++mt) {
    const int m0 = cbase + (mt << 6);
    u64 k0[16], k1[16];
    #pragma unroll
    for (int cb = 0; cb < 4; ++cb) {
      const bf16* crh = xhb + (size_t)(m0 + cb * 16 + col) * CIN + quad * 8;
      const bf16* crl = xlb + (size_t)(m0 + cb * 16 + col) * CIN + quad * 8;
      f32x4 a0 = {0.f, 0.f, 0.f, 0.f};
      f32x4 a1 = {0.f, 0.f, 0.f, 0.f};
      #pragma unroll
      for (int ks = 0; ks < 4; ++ks) {
        const bf16x8 ch_ = *(const bf16x8*)(crh + ks * 32);
        const bf16x8 cl_ = *(const bf16x8*)(crl + ks * 32);
        a0 = MFMA16x16(cl_, qh[0][ks], a0);
        a0 = MFMA16x16(ch_, ql[0][ks], a0);
        a0 = MFMA16x16(ch_, qh[0][ks], a0);
        a1 = MFMA16x16(cl_, qh[1][ks], a1);
        a1 = MFMA16x16(ch_, ql[1][ks], a1);
        a1 = MFMA16x16(ch_, qh[1][ks], a1);
      }
      const f32x4 sqm = *(const f32x4*)(sqb + m0 + cb * 16 + quad * 4);
      #pragma unroll
      for (int r = 0; r < 4; ++r) {
        const int m = m0 + cb * 16 + quad * 4 + r;
        k0[cb * 4 + r] = mk_key((sqn[0] + sqm[r]) - 2.0f * a0[r], m);
        k1[cb * 4 + r] = mk_key((sqn[1] + sqm[r]) - 2.0f * a1[r], m);
      }
    }
    sort16(k0);
    sort16(k1);
    if (mt == 0) {
      #pragma unroll
      for (int i = 0; i < 16; ++i) { R0[i] = k0[i]; R1[i] = k1[i]; }
    } else {
      merge16(R0, k0);
      merge16(R1, k1);
    }
  }

  // in-wave butterfly merge across quads (lists per quad are disjoint cands)
  {
    u64 P[16];
    #pragma unroll
    for (int i = 0; i < 16; ++i) P[i] = __shfl_xor((u64)R0[i], 16);
    merge16(R0, P);
    #pragma unroll
    for (int i = 0; i < 16; ++i) P[i] = __shfl_xor((u64)R0[i], 32);
    merge16(R0, P);
    #pragma unroll
    for (int i = 0; i < 16; ++i) P[i] = __shfl_xor((u64)R1[i], 16);
    merge16(R1, P);
    #pragma unroll
    for (int i = 0; i < 16; ++i) P[i] = __shfl_xor((u64)R1[i], 32);
    merge16(R1, P);
  }
  // all quad-lanes hold the wave-level list; quad 0 publishes run w
  if (quad == 0) {
    #pragma unroll
    for (int i = 0; i < 16; ++i) {
      Lk[col][w * 16 + i]      = R0[i];
      Lk[16 | col][w * 16 + i] = R1[i];
    }
  }
  __syncthreads();

  // 3-level parallel tree merge: 8 -> 4 -> 2 -> 1 runs per query
  {
    u64 A[16], Bv[16];
    const bool act = tid < 128;
    const int q = tid >> 2, j = tid & 3;
    if (act) {
      #pragma unroll
      for (int i = 0; i < 16; ++i) {
        A[i]  = Lk[q][(2 * j) * 16 + i];
        Bv[i] = Lk[q][(2 * j + 1) * 16 + i];
      }
    }
    __syncthreads();
    if (act) {
      merge16(A, Bv);
      #pragma unroll
      for (int i = 0; i < 16; ++i) Lk[q][j * 16 + i] = A[i];
    }
    __syncthreads();
  }
  {
    u64 A[16], Bv[16];
    const bool act = tid < 64;
    const int q = tid >> 1, j = tid & 1;
    if (act) {
      #pragma unroll
      for (int i = 0; i < 16; ++i) {
        A[i]  = Lk[q][(2 * j) * 16 + i];
        Bv[i] = Lk[q][(2 * j + 1) * 16 + i];
      }
    }
    __syncthreads();
    if (act) {
      merge16(A, Bv);
      #pragma unroll
      for (int i = 0; i < 16; ++i) Lk[q][j * 16 + i] = A[i];
    }
    __syncthreads();
  }
  if (tid < 32) {
    u64 A[16], Bv[16];
    #pragma unroll
    for (int i = 0; i < 16; ++i) { A[i] = Lk[tid][i]; Bv[i] = Lk[tid][16 + i]; }
    merge16(A, Bv);
    int* op = knn_idx + (size_t)(b * NPT + q0 + tid) * KNBR;
    #pragma unroll
    for (int i = 0; i < 16; ++i) op[i] = (int)(A[i] & 0xFFFFFFFFull);
  }
}

// ---------------------------------------------------------------------------
// K2: edge MLP + attention + aggregate. 512-thr blocks (8 waves), one wave
// per point, 4 points per wave. We (64 KB) staged once per block into padded
// LDS (264-elem rows -> only 2-way b128 conflicts) -> removes ~1 GB of L2
// We re-reads. A-fragments built in registers; no barriers in point loop.
// ---------------------------------------------------------------------------
__global__ __launch_bounds__(512, 4) void k_edge(const bf16* __restrict__ xh,
                                                 const bf16* __restrict__ xl,
                                                 const int* __restrict__ knn_idx,
                                                 const bf16* __restrict__ We,
                                                 const float* __restrict__ g1, const float* __restrict__ b1,
                                                 const float* __restrict__ m1, const float* __restrict__ v1,
                                                 const float* __restrict__ watt,
                                                 bf16* __restrict__ agg) {
  __shared__ __attribute__((aligned(16))) bf16 sWe[128][264];
  __shared__ float s1[HED], t1[HED], wat[HED];
  const int tid  = threadIdx.x;
  const int w    = tid >> 6;
  const int lane = tid & 63;
  const int col  = lane & 15;
  const int quad = lane >> 4;
  if (tid < HED) {
    const float ss = g1[tid] / sqrtf(v1[tid] + 1e-5f);
    s1[tid] = ss;
    t1[tid] = b1[tid] - m1[tid] * ss;
    wat[tid] = watt[tid];
  }
  // stage We (128 x 256 bf16) into LDS, coalesced 16B per thread per rep
  #pragma unroll
  for (int rep = 0; rep < 8; ++rep) {
    const int i = rep * 512 + tid;       // [0, 4096) vec8 slots
    const int r = i >> 5;                // row
    const int e = i & 31;                // vec8 within row
    *(bf16x8*)&sWe[r][e * 8] = *(const bf16x8*)(We + (size_t)r * 256 + e * 8);
  }
  __syncthreads();
  const int gw = blockIdx.x * 8 + w;
  for (int it = 0; it < 4; ++it) {
    const int p = gw * 4 + it;
    const int b = p >> 12;
    const int n = p & 4095;
    const bf16* xhb = xh + (size_t)b * NPT * CIN;
    const bf16* xlb = xl + (size_t)b * NPT * CIN;
    const int m = knn_idx[(size_t)p * KNBR + col];   // neighbor col of point p
    const bf16* nh  = xhb + (size_t)m * CIN + quad * 8;
    const bf16* nl_ = xlb + (size_t)m * CIN + quad * 8;
    const bf16* ch  = xhb + (size_t)n * CIN + quad * 8;
    const bf16* cl  = xlb + (size_t)n * CIN + quad * 8;
    bf16x8 af[8];
    #pragma unroll
    for (int ks = 0; ks < 4; ++ks) {
      const bf16x8 nhv = *(const bf16x8*)(nh + ks * 32);
      const bf16x8 nlv = *(const bf16x8*)(nl_ + ks * 32);
      const bf16x8 chv = *(const bf16x8*)(ch + ks * 32);
      const bf16x8 clv = *(const bf16x8*)(cl + ks * 32);
      bf16x8 dv, cv;
      #pragma unroll
      for (int e = 0; e < 8; ++e) {
        const float nf = (float)nhv[e] + (float)nlv[e];
        const float cf = (float)chv[e] + (float)clv[e];
        dv[e] = (bf16)(nf - cf);
        cv[e] = (bf16)cf;
      }
      af[ks]     = dv;   // edge channels [0,128): neigh - center
      af[4 + ks] = cv;   // edge channels [128,256): center
    }
    const f32x4 zero4 = {0.f, 0.f, 0.f, 0.f};
    f32x4 acc[8];
    #pragma unroll
    for (int hb = 0; hb < 8; ++hb) acc[hb] = zero4;
    #pragma unroll
    for (int ks = 0; ks < 8; ++ks) {
      #pragma unroll
      for (int hb = 0; hb < 8; ++hb) {
        const bf16x8 bfv = *(const bf16x8*)&sWe[hb * 16 + col][ks * 32 + quad * 8];
        acc[hb] = MFMA16x16(af[ks], bfv, acc[hb]);
      }
    }
    float h[8][4];
    float lg[4] = {0.f, 0.f, 0.f, 0.f};
    #pragma unroll
    for (int hb = 0; hb < 8; ++hb) {
      const int hc = hb * 16 + col;
      const float ss = s1[hc], tt = t1[hc], ww = wat[hc];
      #pragma unroll
      for (int r = 0; r < 4; ++r) {
        const float hv = fmaxf(acc[hb][r] * ss + tt, 0.f);
        h[hb][r] = hv;
        lg[r] += hv * ww;
      }
    }
    #pragma unroll
    for (int r = 0; r < 4; ++r) {
      float vv = lg[r];
      vv += __shfl_xor(vv, 1);
      vv += __shfl_xor(vv, 2);
      vv += __shfl_xor(vv, 4);
      vv += __shfl_xor(vv, 8);
      lg[r] = vv;
    }
    float mx = fmaxf(fmaxf(lg[0], lg[1]), fmaxf(lg[2], lg[3]));
    mx = fmaxf(mx, __shfl_xor(mx, 16));
    mx = fmaxf(mx, __shfl_xor(mx, 32));
    float ex[4];
    float sm = 0.f;
    #pragma unroll
    for (int r = 0; r < 4; ++r) { ex[r] = expf(lg[r] - mx); sm += ex[r]; }
    sm += __shfl_xor(sm, 16);
    sm += __shfl_xor(sm, 32);
    const float inv = 1.0f / sm;
    float ag[8];
    #pragma unroll
    for (int hb = 0; hb < 8; ++hb) {
      float a = h[hb][0] * ex[0] + h[hb][1] * ex[1] + h[hb][2] * ex[2] + h[hb][3] * ex[3];
      a += __shfl_xor(a, 16);
      a += __shfl_xor(a, 32);
      ag[hb] = a * inv;
    }
    if (quad == 0) {
      bf16* ao = agg + (size_t)p * HED;
      #pragma unroll
      for (int hb = 0; hb < 8; ++hb) ao[hb * 16 + col] = (bf16)ag[hb];
    }
  }
}

// ---------------------------------------------------------------------------
// K3: fuse GEMM (B*N,128)x(128,256) + bn2 + relu -> outp bf16.
// 2 waves share a 16-row tile, splitting the 16 ob-blocks -> 2048 waves.
// ---------------------------------------------------------------------------
__global__ __launch_bounds__(256) void k_fuse(const bf16* __restrict__ agg,
                                              const bf16* __restrict__ Wf,
                                              const float* __restrict__ g2, const float* __restrict__ b2,
                                              const float* __restrict__ m2, const float* __restrict__ v2,
                                              bf16* __restrict__ outp) {
  const int tid  = threadIdx.x;
  const int w    = tid >> 6;
  const int lane = tid & 63;
  const int col  = lane & 15;
  const int quad = lane >> 4;
  const int p0   = (blockIdx.x * 2 + (w >> 1)) * 16;
  const int obb  = (w & 1) * 8;
  bf16x8 afr[4];
  const bf16* arow = agg + (size_t)(p0 + col) * HED + quad * 8;
  #pragma unroll
  for (int ks = 0; ks < 4; ++ks) afr[ks] = *(const bf16x8*)(arow + ks * 32);
  #pragma unroll
  for (int obi = 0; obi < 8; ++obi) {
    const int ob = obb + obi;
    f32x4 acc = {0.f, 0.f, 0.f, 0.f};
    const bf16* brow = Wf + (size_t)(ob * 16 + col) * HED + quad * 8;
    #pragma unroll
    for (int ks = 0; ks < 4; ++ks)
      acc = MFMA16x16(afr[ks], *(const bf16x8*)(brow + ks * 32), acc);
    const int o = ob * 16 + col;
    const float ss = g2[o] / sqrtf(v2[o] + 1e-5f);
    const float tt = b2[o] - m2[o] * ss;
    #pragma unroll
    for (int r = 0; r < 4; ++r) {
      outp[(size_t)(p0 + quad * 4 + r) * COUT + o] = (bf16)fmaxf(acc[r] * ss + tt, 0.f);
    }
  }
}

// ---------------------------------------------------------------------------
// K4: SE. One block per (b, chunk): mean over 256 pts -> fc1+relu -> fc2+sigmoid
// ---------------------------------------------------------------------------
__global__ __launch_bounds__(256) void k_se(const bf16* __restrict__ outp,
                                            const float* __restrict__ f1w, const float* __restrict__ f1b,
                                            const float* __restrict__ f2w, const float* __restrict__ f2b,
                                            float* __restrict__ sse) {
  __shared__ float mean_s[COUT];
  __shared__ float h1[64];
  const int bc  = blockIdx.x;   // b*16 + chunk
  const int tid = threadIdx.x;
  const bf16* base = outp + (size_t)bc * 256 * COUT;
  float s = 0.f;
  for (int p2 = 0; p2 < 256; ++p2) s += (float)base[(size_t)p2 * COUT + tid];
  mean_s[tid] = s * (1.0f / 256.0f);
  __syncthreads();
  if (tid < 64) {
    float a = f1b[tid];
    for (int c = 0; c < COUT; ++c) a += f1w[tid * COUT + c] * mean_s[c];
    h1[tid] = fmaxf(a, 0.f);
  }
  __syncthreads();
  float a = f2b[tid];
  #pragma unroll
  for (int j = 0; j < 64; ++j) a += f2w[tid * 64 + j] * h1[j];
  sse[(size_t)bc * COUT + tid] = 1.0f / (1.0f + expf(-a));
}

// ---------------------------------------------------------------------------
// K5: residual GEMM + bn3; out = outp*se + res, fp32, transposed (B,Cout,N).
// 2 waves share a 16-row tile, splitting the 16 ob-blocks -> 2048 waves.
// ---------------------------------------------------------------------------
__global__ __launch_bounds__(256) void k_final(const bf16* __restrict__ xh,
                                               const bf16* __restrict__ Wr,
                                               const float* __restrict__ g3, const float* __restrict__ b3,
                                               const float* __restrict__ m3, const float* __restrict__ v3,
                                               const bf16* __restrict__ outp,
                                               const float* __restrict__ sse,
                                               float* __restrict__ out) {
  const int tid  = threadIdx.x;
  const int w    = tid >> 6;
  const int lane = tid & 63;
  const int col  = lane & 15;
  const int quad = lane >> 4;
  const int p0   = (blockIdx.x * 2 + (w >> 1)) * 16;
  const int obb  = (w & 1) * 8;
  const int b    = p0 >> 12;
  const int n0l  = p0 & 4095;
  bf16x8 afr[4];
  const bf16* arow = xh + (size_t)(p0 + col) * CIN + quad * 8;
  #pragma unroll
  for (int ks = 0; ks < 4; ++ks) afr[ks] = *(const bf16x8*)(arow + ks * 32);
  const float* scb = sse + (size_t)(b * 16 + (n0l >> 8)) * COUT;
  #pragma unroll
  for (int obi = 0; obi < 8; ++obi) {
    const int ob = obb + obi;
    f32x4 acc = {0.f, 0.f, 0.f, 0.f};
    const bf16* brow = Wr + (size_t)(ob * 16 + col) * CIN + quad * 8;
    #pragma unroll
    for (int ks = 0; ks < 4; ++ks)
      acc = MFMA16x16(afr[ks], *(const bf16x8*)(brow + ks * 32), acc);
    const int o = ob * 16 + col;
    const float ss = g3[o] / sqrtf(v3[o] + 1e-5f);
    const float tt = b3[o] - m3[o] * ss;
    const float sc = scb[o];
    f32x4 pk;
    #pragma unroll
    for (int r = 0; r < 4; ++r) {
      const float res = acc[r] * ss + tt;
      pk[r] = (float)outp[(size_t)(p0 + quad * 4 + r) * COUT + o] * sc + res;
    }
    float* op = out + (size_t)(b * COUT + o) * NPT + n0l + quad * 4;
    *(f32x4*)op = pk;
  }
}

// ---------------------------------------------------------------------------
extern "C" void kernel_launch(void* const* d_in, const int* in_sizes, int n_in,
                              void* d_out, int out_size, void* d_ws, size_t ws_size,
                              hipStream_t stream) {
  (void)in_sizes; (void)n_in; (void)out_size; (void)ws_size;
  const float* x    = (const float*)d_in[0];
  const float* We   = (const float*)d_in[1];
  const float* g1   = (const float*)d_in[2];
  const float* b1   = (const float*)d_in[3];
  const float* m1   = (const float*)d_in[4];
  const float* v1   = (const float*)d_in[5];
  const float* watt = (const float*)d_in[6];
  const float* Wf   = (const float*)d_in[7];
  const float* g2   = (const float*)d_in[8];
  const float* b2   = (const float*)d_in[9];
  const float* m2   = (const float*)d_in[10];
  const float* v2   = (const float*)d_in[11];
  const float* f1w  = (const float*)d_in[12];
  const float* f1b  = (const float*)d_in[13];
  const float* f2w  = (const float*)d_in[14];
  const float* f2b  = (const float*)d_in[15];
  const float* Wr   = (const float*)d_in[16];
  const float* g3   = (const float*)d_in[17];
  const float* b3   = (const float*)d_in[18];
  const float* m3   = (const float*)d_in[19];
  const float* v3   = (const float*)d_in[20];

  char* ws = (char*)d_ws;
  size_t off = 0;
  bf16*  xth  = (bf16*)(ws + off);  off += (size_t)BB * NPT * CIN * 2;        // 4 MB
  bf16*  xtl  = (bf16*)(ws + off);  off += (size_t)BB * NPT * CIN * 2;        // 4 MB
  float* sq   = (float*)(ws + off); off += (size_t)BB * NPT * 4;              // 64 KB
  int*   idxp = (int*)(ws + off);   off += (size_t)BB * NPT * KNBR * 4;       // 1 MB
  bf16*  aggp = (bf16*)(ws + off);  off += (size_t)BB * NPT * HED * 2;        // 4 MB
  bf16*  outp = (bf16*)(ws + off);  off += (size_t)BB * NPT * COUT * 2;       // 8 MB
  float* ssep = (float*)(ws + off); off += (size_t)BB * 16 * COUT * 4;        // 64 KB
  bf16*  Web  = (bf16*)(ws + off);  off += (size_t)HED * 2 * CIN * 2;         // 64 KB
  bf16*  Wfb  = (bf16*)(ws + off);  off += (size_t)COUT * HED * 2;            // 64 KB
  bf16*  Wrb  = (bf16*)(ws + off);  off += (size_t)COUT * CIN * 2;            // 64 KB

  float* out = (float*)d_out;

  k_wconv<<<384, 256, 0, stream>>>(We, Wf, Wr, Web, Wfb, Wrb);
  k_prep<<<256, 256, 0, stream>>>(x, xth, xtl, sq);
  k_knn<<<512, 512, 0, stream>>>(xth, xtl, sq, idxp);
  k_edge<<<512, 512, 0, stream>>>(xth, xtl, idxp, Web, g1, b1, m1, v1, watt, aggp);
  k_fuse<<<512, 256, 0, stream>>>(aggp, Wfb, g2, b2, m2, v2, outp);
  k_se<<<64, 256, 0, stream>>>(outp, f1w, f1b, f2w, f2b, ssep);
  k_final<<<512, 256, 0, stream>>>(xth, Wrb, g3, b3, m3, v3, outp, ssep, out);
}

// Round 9
// 454.466 us; speedup vs baseline: 1.8321x; 1.8321x over previous
//
#include <hip/hip_runtime.h>
#include <cstddef>

typedef __bf16 bf16;
typedef __bf16 bf16x8 __attribute__((ext_vector_type(8)));
typedef float  f32x4  __attribute__((ext_vector_type(4)));
typedef unsigned short u16;
typedef unsigned long long u64;

#define MFMA16x16(a, b, c) __builtin_amdgcn_mfma_f32_16x16x32_bf16((a), (b), (c), 0, 0, 0)

namespace {
constexpr int BB   = 4;     // batch
constexpr int CIN  = 128;   // input channels
constexpr int NPT  = 4096;  // points
constexpr int KNBR = 16;    // neighbors
constexpr int HED  = 128;   // hidden (edge mlp out)
constexpr int COUT = 256;   // output channels
}

// ordered-float transform: monotone uint32 over all finite floats
__device__ __forceinline__ unsigned int ord_f32(float f) {
  unsigned int b = __float_as_uint(f);
  return b ^ (0x80000000u | (unsigned int)((int)b >> 31));
}
__device__ __forceinline__ u64 mk_key(float d, int m) {
  return ((u64)ord_f32(d) << 32) | (unsigned int)m;
}

// branch-free bitonic sort of 16 u64 keys, ascending
__device__ __forceinline__ void sort16(u64* k) {
  #pragma unroll
  for (int sz = 2; sz <= 16; sz <<= 1) {
    #pragma unroll
    for (int st = sz >> 1; st > 0; st >>= 1) {
      #pragma unroll
      for (int i = 0; i < 16; ++i) {
        const int j = i ^ st;
        if (j > i) {
          const bool up = ((i & sz) == 0);
          const u64 a = k[i], c = k[j];
          const bool sw = up ? (a > c) : (a < c);
          k[i] = sw ? c : a;
          k[j] = sw ? a : c;
        }
      }
    }
  }
}

// R (sorted asc 16) <- lowest 16 of R ∪ B (B sorted asc), sorted asc
__device__ __forceinline__ void merge16(u64* R, const u64* B) {
  u64 t[16];
  #pragma unroll
  for (int i = 0; i < 16; ++i) {
    const u64 a = R[i], c = B[15 - i];
    t[i] = (a < c) ? a : c;          // half-cleaner: lower half, bitonic
  }
  #pragma unroll
  for (int st = 8; st > 0; st >>= 1) {
    #pragma unroll
    for (int i = 0; i < 16; ++i) {
      const int j = i ^ st;
      if (j > i) {
        const u64 a = t[i], c = t[j];
        const bool sw = a > c;
        t[i] = sw ? c : a;
        t[j] = sw ? a : c;
      }
    }
  }
  #pragma unroll
  for (int i = 0; i < 16; ++i) R[i] = t[i];
}

// ---------------------------------------------------------------------------
// W0: convert the three GEMM weight matrices fp32 -> bf16 (each 32768 elems)
// ---------------------------------------------------------------------------
__global__ __launch_bounds__(256) void k_wconv(const float* __restrict__ We,
                                               const float* __restrict__ Wf,
                                               const float* __restrict__ Wr,
                                               bf16* __restrict__ Web,
                                               bf16* __restrict__ Wfb,
                                               bf16* __restrict__ Wrb) {
  const int i = blockIdx.x * 256 + threadIdx.x;   // [0, 3*32768)
  const int a = i >> 15;
  const int j = i & 32767;
  const float* src = (a == 0) ? We : (a == 1) ? Wf : Wr;
  bf16*        dst = (a == 0) ? Web : (a == 1) ? Wfb : Wrb;
  dst[j] = (bf16)src[j];
}

// ---------------------------------------------------------------------------
// K0: transpose x (B,Cin,N) fp32 -> xt_hi/xt_lo (B,N,Cin) bf16 split, and
//     sq[b][n] = sum_c x^2 in fp32 (matches reference's fp32 sq).
// ---------------------------------------------------------------------------
__global__ __launch_bounds__(256) void k_prep(const float* __restrict__ x,
                                              bf16* __restrict__ xh,
                                              bf16* __restrict__ xl,
                                              float* __restrict__ sq) {
  __shared__ __attribute__((aligned(16))) bf16 th[64][136];
  __shared__ __attribute__((aligned(16))) bf16 tl[64][136];
  __shared__ float sqp[4][64];
  const int tid = threadIdx.x;
  const int b   = blockIdx.x >> 6;
  const int n0  = (blockIdx.x & 63) << 6;
  const int nl  = tid & 63;
  const int cg  = tid >> 6;
  const float* xb = x + (size_t)b * CIN * NPT;
  float acc = 0.f;
  #pragma unroll
  for (int rep = 0; rep < 32; ++rep) {
    const int c = rep * 4 + cg;
    const float v = xb[(size_t)c * NPT + n0 + nl];
    const bf16 h = (bf16)v;
    const bf16 l = (bf16)(v - (float)h);
    acc += v * v;
    th[nl][c] = h;
    tl[nl][c] = l;
  }
  sqp[cg][nl] = acc;
  __syncthreads();
  bf16* xho = xh + ((size_t)b * NPT + n0) * CIN;
  bf16* xlo = xl + ((size_t)b * NPT + n0) * CIN;
  #pragma unroll
  for (int rep = 0; rep < 32; ++rep) {
    const int e = rep * 256 + tid;
    const int r = e >> 7;
    const int c = e & 127;
    xho[(size_t)r * CIN + c] = th[r][c];
    xlo[(size_t)r * CIN + c] = tl[r][c];
  }
  if (tid < 64) {
    sq[b * NPT + n0 + tid] = sqp[0][tid] + sqp[1][tid] + sqp[2][tid] + sqp[3][tid];
  }
}

// ---------------------------------------------------------------------------
// K1: KNN v9 = round-4 compute (256 thr, 4 waves, 32 queries, dual 16-query
// lists/wave; wave w scans cands [w*1024,(w+1)*1024)) + r5's in-register
// quad butterfly merge -> LDS shrinks 66 KB -> 16.6 KB, so residency is
// VGPR-bound (128 @ launch_bounds(256,2) -> 4 blocks/CU = 16 waves/CU, 2x r4).
// MFMA A=candidates, B=queries -> Gram in accumulators. Per lane per 64-cand
// tile: 16 packed u64 keys bitonic-sorted, merged (lowest-16) into running
// lists. Cross-quad merge via shfl_xor(16/32) butterfly; cross-wave via LDS
// (4 runs/query) + 32-lane chain merge.
// Key order = lexicographic (d, idx) -> exact lax.top_k tie semantics.
// Split-bf16 (hh+hl+lh) Gram: d2 err ~1e-4 << rank-16/17 gap.
// ---------------------------------------------------------------------------
__global__ __launch_bounds__(256, 2) void k_knn(const bf16* __restrict__ xh,
                                                const bf16* __restrict__ xl,
                                                const float* __restrict__ sq,
                                                int* __restrict__ knn_idx) {
  __shared__ u64 Lk[32][65];   // 32 queries x 4 wave-runs x 16 keys (+pad)
  const int tid  = threadIdx.x;
  const int w    = tid >> 6;
  const int lane = tid & 63;
  const int col  = lane & 15;
  const int quad = lane >> 4;
  const int b    = blockIdx.x >> 7;          // 128 blocks per batch
  const int q0   = (blockIdx.x & 127) << 5;  // 32 queries per block
  const bf16*  xhb = xh + (size_t)b * NPT * CIN;
  const bf16*  xlb = xl + (size_t)b * NPT * CIN;
  const float* sqb = sq + b * NPT;

  // query fragments (B operand), 2 subtiles of 16 queries
  bf16x8 qh[2][4], ql[2][4];
  float sqn[2];
  #pragma unroll
  for (int t = 0; t < 2; ++t) {
    const bf16* qrh = xhb + (size_t)(q0 + t * 16 + col) * CIN + quad * 8;
    const bf16* qrl = xlb + (size_t)(q0 + t * 16 + col) * CIN + quad * 8;
    #pragma unroll
    for (int ks = 0; ks < 4; ++ks) {
      qh[t][ks] = *(const bf16x8*)(qrh + ks * 32);
      ql[t][ks] = *(const bf16x8*)(qrl + ks * 32);
    }
    sqn[t] = sqb[q0 + t * 16 + col];
  }

  u64 R0[16], R1[16];
  const int cbase = w << 10;
  for (int mt = 0; mt < 16; ++mt) {
    const int m0 = cbase + (mt << 6);
    u64 k0[16], k1[16];
    #pragma unroll
    for (int cb = 0; cb < 4; ++cb) {
      const bf16* crh = xhb + (size_t)(m0 + cb * 16 + col) * CIN + quad * 8;
      const bf16* crl = xlb + (size_t)(m0 + cb * 16 + col) * CIN + quad * 8;
      f32x4 a0 = {0.f, 0.f, 0.f, 0.f};
      f32x4 a1 = {0.f, 0.f, 0.f, 0.f};
      #pragma unroll
      for (int ks = 0; ks < 4; ++ks) {
        const bf16x8 ch_ = *(const bf16x8*)(crh + ks * 32);
        const bf16x8 cl_ = *(const bf16x8*)(crl + ks * 32);
        a0 = MFMA16x16(cl_, qh[0][ks], a0);
        a0 = MFMA16x16(ch_, ql[0][ks], a0);
        a0 = MFMA16x16(ch_, qh[0][ks], a0);
        a1 = MFMA16x16(cl_, qh[1][ks], a1);
        a1 = MFMA16x16(ch_, ql[1][ks], a1);
        a1 = MFMA16x16(ch_, qh[1][ks], a1);
      }
      const f32x4 sqm = *(const f32x4*)(sqb + m0 + cb * 16 + quad * 4);
      #pragma unroll
      for (int r = 0; r < 4; ++r) {
        const int m = m0 + cb * 16 + quad * 4 + r;
        k0[cb * 4 + r] = mk_key((sqn[0] + sqm[r]) - 2.0f * a0[r], m);
        k1[cb * 4 + r] = mk_key((sqn[1] + sqm[r]) - 2.0f * a1[r], m);
      }
    }
    sort16(k0);
    sort16(k1);
    if (mt == 0) {
      #pragma unroll
      for (int i = 0; i < 16; ++i) { R0[i] = k0[i]; R1[i] = k1[i]; }
    } else {
      merge16(R0, k0);
      merge16(R1, k1);
    }
  }

  // in-wave butterfly merge across quads (lists per quad are disjoint cands)
  {
    u64 P[16];
    #pragma unroll
    for (int i = 0; i < 16; ++i) P[i] = __shfl_xor((u64)R0[i], 16);
    merge16(R0, P);
    #pragma unroll
    for (int i = 0; i < 16; ++i) P[i] = __shfl_xor((u64)R0[i], 32);
    merge16(R0, P);
    #pragma unroll
    for (int i = 0; i < 16; ++i) P[i] = __shfl_xor((u64)R1[i], 16);
    merge16(R1, P);
    #pragma unroll
    for (int i = 0; i < 16; ++i) P[i] = __shfl_xor((u64)R1[i], 32);
    merge16(R1, P);
  }
  // all quad-lanes hold the wave-level list; quad 0 publishes run w
  if (quad == 0) {
    #pragma unroll
    for (int i = 0; i < 16; ++i) {
      Lk[col][w * 16 + i]      = R0[i];
      Lk[16 | col][w * 16 + i] = R1[i];
    }
  }
  __syncthreads();

  // cross-wave merge: 32 lanes, one query each, chain of 3 merge16s
  if (tid < 32) {
    u64 A[16], Bv[16];
    #pragma unroll
    for (int i = 0; i < 16; ++i) A[i] = Lk[tid][i];
    #pragma unroll
    for (int run = 1; run < 4; ++run) {
      #pragma unroll
      for (int i = 0; i < 16; ++i) Bv[i] = Lk[tid][run * 16 + i];
      merge16(A, Bv);
    }
    int* op = knn_idx + (size_t)(b * NPT + q0 + tid) * KNBR;
    #pragma unroll
    for (int i = 0; i < 16; ++i) op[i] = (int)(A[i] & 0xFFFFFFFFull);
  }
}

// ---------------------------------------------------------------------------
// K2: edge MLP + attention + aggregate. 512-thr blocks (8 waves), one wave
// per point, 4 points per wave. We (64 KB) staged once per block into padded
// LDS (264-elem rows -> only 2-way b128 conflicts). A-fragments built in
// registers; no barriers in point loop. launch_bounds(512,2) -> VGPR cap 128
// (no spill; r8's (512,4) capped at 64).
// ---------------------------------------------------------------------------
__global__ __launch_bounds__(512, 2) void k_edge(const bf16* __restrict__ xh,
                                                 const bf16* __restrict__ xl,
                                                 const int* __restrict__ knn_idx,
                                                 const bf16* __restrict__ We,
                                                 const float* __restrict__ g1, const float* __restrict__ b1,
                                                 const float* __restrict__ m1, const float* __restrict__ v1,
                                                 const float* __restrict__ watt,
                                                 bf16* __restrict__ agg) {
  __shared__ __attribute__((aligned(16))) bf16 sWe[128][264];
  __shared__ float s1[HED], t1[HED], wat[HED];
  const int tid  = threadIdx.x;
  const int w    = tid >> 6;
  const int lane = tid & 63;
  const int col  = lane & 15;
  const int quad = lane >> 4;
  if (tid < HED) {
    const float ss = g1[tid] / sqrtf(v1[tid] + 1e-5f);
    s1[tid] = ss;
    t1[tid] = b1[tid] - m1[tid] * ss;
    wat[tid] = watt[tid];
  }
  // stage We (128 x 256 bf16) into LDS, coalesced 16B per thread per rep
  #pragma unroll
  for (int rep = 0; rep < 8; ++rep) {
    const int i = rep * 512 + tid;       // [0, 4096) vec8 slots
    const int r = i >> 5;                // row
    const int e = i & 31;                // vec8 within row
    *(bf16x8*)&sWe[r][e * 8] = *(const bf16x8*)(We + (size_t)r * 256 + e * 8);
  }
  __syncthreads();
  const int gw = blockIdx.x * 8 + w;
  for (int it = 0; it < 4; ++it) {
    const int p = gw * 4 + it;
    const int b = p >> 12;
    const int n = p & 4095;
    const bf16* xhb = xh + (size_t)b * NPT * CIN;
    const bf16* xlb = xl + (size_t)b * NPT * CIN;
    const int m = knn_idx[(size_t)p * KNBR + col];   // neighbor col of point p
    const bf16* nh  = xhb + (size_t)m * CIN + quad * 8;
    const bf16* nl_ = xlb + (size_t)m * CIN + quad * 8;
    const bf16* ch  = xhb + (size_t)n * CIN + quad * 8;
    const bf16* cl  = xlb + (size_t)n * CIN + quad * 8;
    bf16x8 af[8];
    #pragma unroll
    for (int ks = 0; ks < 4; ++ks) {
      const bf16x8 nhv = *(const bf16x8*)(nh + ks * 32);
      const bf16x8 nlv = *(const bf16x8*)(nl_ + ks * 32);
      const bf16x8 chv = *(const bf16x8*)(ch + ks * 32);
      const bf16x8 clv = *(const bf16x8*)(cl + ks * 32);
      bf16x8 dv, cv;
      #pragma unroll
      for (int e = 0; e < 8; ++e) {
        const float nf = (float)nhv[e] + (float)nlv[e];
        const float cf = (float)chv[e] + (float)clv[e];
        dv[e] = (bf16)(nf - cf);
        cv[e] = (bf16)cf;
      }
      af[ks]     = dv;   // edge channels [0,128): neigh - center
      af[4 + ks] = cv;   // edge channels [128,256): center
    }
    const f32x4 zero4 = {0.f, 0.f, 0.f, 0.f};
    f32x4 acc[8];
    #pragma unroll
    for (int hb = 0; hb < 8; ++hb) acc[hb] = zero4;
    #pragma unroll
    for (int ks = 0; ks < 8; ++ks) {
      #pragma unroll
      for (int hb = 0; hb < 8; ++hb) {
        const bf16x8 bfv = *(const bf16x8*)&sWe[hb * 16 + col][ks * 32 + quad * 8];
        acc[hb] = MFMA16x16(af[ks], bfv, acc[hb]);
      }
    }
    float h[8][4];
    float lg[4] = {0.f, 0.f, 0.f, 0.f};
    #pragma unroll
    for (int hb = 0; hb < 8; ++hb) {
      const int hc = hb * 16 + col;
      const float ss = s1[hc], tt = t1[hc], ww = wat[hc];
      #pragma unroll
      for (int r = 0; r < 4; ++r) {
        const float hv = fmaxf(acc[hb][r] * ss + tt, 0.f);
        h[hb][r] = hv;
        lg[r] += hv * ww;
      }
    }
    #pragma unroll
    for (int r = 0; r < 4; ++r) {
      float vv = lg[r];
      vv += __shfl_xor(vv, 1);
      vv += __shfl_xor(vv, 2);
      vv += __shfl_xor(vv, 4);
      vv += __shfl_xor(vv, 8);
      lg[r] = vv;
    }
    float mx = fmaxf(fmaxf(lg[0], lg[1]), fmaxf(lg[2], lg[3]));
    mx = fmaxf(mx, __shfl_xor(mx, 16));
    mx = fmaxf(mx, __shfl_xor(mx, 32));
    float ex[4];
    float sm = 0.f;
    #pragma unroll
    for (int r = 0; r < 4; ++r) { ex[r] = expf(lg[r] - mx); sm += ex[r]; }
    sm += __shfl_xor(sm, 16);
    sm += __shfl_xor(sm, 32);
    const float inv = 1.0f / sm;
    float ag[8];
    #pragma unroll
    for (int hb = 0; hb < 8; ++hb) {
      float a = h[hb][0] * ex[0] + h[hb][1] * ex[1] + h[hb][2] * ex[2] + h[hb][3] * ex[3];
      a += __shfl_xor(a, 16);
      a += __shfl_xor(a, 32);
      ag[hb] = a * inv;
    }
    if (quad == 0) {
      bf16* ao = agg + (size_t)p * HED;
      #pragma unroll
      for (int hb = 0; hb < 8; ++hb) ao[hb * 16 + col] = (bf16)ag[hb];
    }
  }
}

// ---------------------------------------------------------------------------
// K3: fuse GEMM (B*N,128)x(128,256) + bn2 + relu -> outp bf16.
// 2 waves share a 16-row tile, splitting the 16 ob-blocks -> 2048 waves.
// ---------------------------------------------------------------------------
__global__ __launch_bounds__(256) void k_fuse(const bf16* __restrict__ agg,
                                              const bf16* __restrict__ Wf,
                                              const float* __restrict__ g2, const float* __restrict__ b2,
                                              const float* __restrict__ m2, const float* __restrict__ v2,
                                              bf16* __restrict__ outp) {
  const int tid  = threadIdx.x;
  const int w    = tid >> 6;
  const int lane = tid & 63;
  const int col  = lane & 15;
  const int quad = lane >> 4;
  const int p0   = (blockIdx.x * 2 + (w >> 1)) * 16;
  const int obb  = (w & 1) * 8;
  bf16x8 afr[4];
  const bf16* arow = agg + (size_t)(p0 + col) * HED + quad * 8;
  #pragma unroll
  for (int ks = 0; ks < 4; ++ks) afr[ks] = *(const bf16x8*)(arow + ks * 32);
  #pragma unroll
  for (int obi = 0; obi < 8; ++obi) {
    const int ob = obb + obi;
    f32x4 acc = {0.f, 0.f, 0.f, 0.f};
    const bf16* brow = Wf + (size_t)(ob * 16 + col) * HED + quad * 8;
    #pragma unroll
    for (int ks = 0; ks < 4; ++ks)
      acc = MFMA16x16(afr[ks], *(const bf16x8*)(brow + ks * 32), acc);
    const int o = ob * 16 + col;
    const float ss = g2[o] / sqrtf(v2[o] + 1e-5f);
    const float tt = b2[o] - m2[o] * ss;
    #pragma unroll
    for (int r = 0; r < 4; ++r) {
      outp[(size_t)(p0 + quad * 4 + r) * COUT + o] = (bf16)fmaxf(acc[r] * ss + tt, 0.f);
    }
  }
}

// ---------------------------------------------------------------------------
// K4: SE. One block per (b, chunk): mean over 256 pts -> fc1+relu -> fc2+sigmoid
// ---------------------------------------------------------------------------
__global__ __launch_bounds__(256) void k_se(const bf16* __restrict__ outp,
                                            const float* __restrict__ f1w, const float* __restrict__ f1b,
                                            const float* __restrict__ f2w, const float* __restrict__ f2b,
                                            float* __restrict__ sse) {
  __shared__ float mean_s[COUT];
  __shared__ float h1[64];
  const int bc  = blockIdx.x;   // b*16 + chunk
  const int tid = threadIdx.x;
  const bf16* base = outp + (size_t)bc * 256 * COUT;
  float s = 0.f;
  for (int p2 = 0; p2 < 256; ++p2) s += (float)base[(size_t)p2 * COUT + tid];
  mean_s[tid] = s * (1.0f / 256.0f);
  __syncthreads();
  if (tid < 64) {
    float a = f1b[tid];
    for (int c = 0; c < COUT; ++c) a += f1w[tid * COUT + c] * mean_s[c];
    h1[tid] = fmaxf(a, 0.f);
  }
  __syncthreads();
  float a = f2b[tid];
  #pragma unroll
  for (int j = 0; j < 64; ++j) a += f2w[tid * 64 + j] * h1[j];
  sse[(size_t)bc * COUT + tid] = 1.0f / (1.0f + expf(-a));
}

// ---------------------------------------------------------------------------
// K5: residual GEMM + bn3; out = outp*se + res, fp32, transposed (B,Cout,N).
// 2 waves share a 16-row tile, splitting the 16 ob-blocks -> 2048 waves.
// ---------------------------------------------------------------------------
__global__ __launch_bounds__(256) void k_final(const bf16* __restrict__ xh,
                                               const bf16* __restrict__ Wr,
                                               const float* __restrict__ g3, const float* __restrict__ b3,
                                               const float* __restrict__ m3, const float* __restrict__ v3,
                                               const bf16* __restrict__ outp,
                                               const float* __restrict__ sse,
                                               float* __restrict__ out) {
  const int tid  = threadIdx.x;
  const int w    = tid >> 6;
  const int lane = tid & 63;
  const int col  = lane & 15;
  const int quad = lane >> 4;
  const int p0   = (blockIdx.x * 2 + (w >> 1)) * 16;
  const int obb  = (w & 1) * 8;
  const int b    = p0 >> 12;
  const int n0l  = p0 & 4095;
  bf16x8 afr[4];
  const bf16* arow = xh + (size_t)(p0 + col) * CIN + quad * 8;
  #pragma unroll
  for (int ks = 0; ks < 4; ++ks) afr[ks] = *(const bf16x8*)(arow + ks * 32);
  const float* scb = sse + (size_t)(b * 16 + (n0l >> 8)) * COUT;
  #pragma unroll
  for (int obi = 0; obi < 8; ++obi) {
    const int ob = obb + obi;
    f32x4 acc = {0.f, 0.f, 0.f, 0.f};
    const bf16* brow = Wr + (size_t)(ob * 16 + col) * CIN + quad * 8;
    #pragma unroll
    for (int ks = 0; ks < 4; ++ks)
      acc = MFMA16x16(afr[ks], *(const bf16x8*)(brow + ks * 32), acc);
    const int o = ob * 16 + col;
    const float ss = g3[o] / sqrtf(v3[o] + 1e-5f);
    const float tt = b3[o] - m3[o] * ss;
    const float sc = scb[o];
    f32x4 pk;
    #pragma unroll
    for (int r = 0; r < 4; ++r) {
      const float res = acc[r] * ss + tt;
      pk[r] = (float)outp[(size_t)(p0 + quad * 4 + r) * COUT + o] * sc + res;
    }
    float* op = out + (size_t)(b * COUT + o) * NPT + n0l + quad * 4;
    *(f32x4*)op = pk;
  }
}

// ---------------------------------------------------------------------------
extern "C" void kernel_launch(void* const* d_in, const int* in_sizes, int n_in,
                              void* d_out, int out_size, void* d_ws, size_t ws_size,
                              hipStream_t stream) {
  (void)in_sizes; (void)n_in; (void)out_size; (void)ws_size;
  const float* x    = (const float*)d_in[0];
  const float* We   = (const float*)d_in[1];
  const float* g1   = (const float*)d_in[2];
  const float* b1   = (const float*)d_in[3];
  const float* m1   = (const float*)d_in[4];
  const float* v1   = (const float*)d_in[5];
  const float* watt = (const float*)d_in[6];
  const float* Wf   = (const float*)d_in[7];
  const float* g2   = (const float*)d_in[8];
  const float* b2   = (const float*)d_in[9];
  const float* m2   = (const float*)d_in[10];
  const float* v2   = (const float*)d_in[11];
  const float* f1w  = (const float*)d_in[12];
  const float* f1b  = (const float*)d_in[13];
  const float* f2w  = (const float*)d_in[14];
  const float* f2b  = (const float*)d_in[15];
  const float* Wr   = (const float*)d_in[16];
  const float* g3   = (const float*)d_in[17];
  const float* b3   = (const float*)d_in[18];
  const float* m3   = (const float*)d_in[19];
  const float* v3   = (const float*)d_in[20];

  char* ws = (char*)d_ws;
  size_t off = 0;
  bf16*  xth  = (bf16*)(ws + off);  off += (size_t)BB * NPT * CIN * 2;        // 4 MB
  bf16*  xtl  = (bf16*)(ws + off);  off += (size_t)BB * NPT * CIN * 2;        // 4 MB
  float* sq   = (float*)(ws + off); off += (size_t)BB * NPT * 4;              // 64 KB
  int*   idxp = (int*)(ws + off);   off += (size_t)BB * NPT * KNBR * 4;       // 1 MB
  bf16*  aggp = (bf16*)(ws + off);  off += (size_t)BB * NPT * HED * 2;        // 4 MB
  bf16*  outp = (bf16*)(ws + off);  off += (size_t)BB * NPT * COUT * 2;       // 8 MB
  float* ssep = (float*)(ws + off); off += (size_t)BB * 16 * COUT * 4;        // 64 KB
  bf16*  Web  = (bf16*)(ws + off);  off += (size_t)HED * 2 * CIN * 2;         // 64 KB
  bf16*  Wfb  = (bf16*)(ws + off);  off += (size_t)COUT * HED * 2;            // 64 KB
  bf16*  Wrb  = (bf16*)(ws + off);  off += (size_t)COUT * CIN * 2;            // 64 KB

  float* out = (float*)d_out;

  k_wconv<<<384, 256, 0, stream>>>(We, Wf, Wr, Web, Wfb, Wrb);
  k_prep<<<256, 256, 0, stream>>>(x, xth, xtl, sq);
  k_knn<<<512, 256, 0, stream>>>(xth, xtl, sq, idxp);
  k_edge<<<512, 512, 0, stream>>>(xth, xtl, idxp, Web, g1, b1, m1, v1, watt, aggp);
  k_fuse<<<512, 256, 0, stream>>>(aggp, Wfb, g2, b2, m2, v2, outp);
  k_se<<<64, 256, 0, stream>>>(outp, f1w, f1b, f2w, f2b, ssep);
  k_final<<<512, 256, 0, stream>>>(xth, Wrb, g3, b3, m3, v3, outp, ssep, out);
}